// Round 1
// baseline (219.161 us; speedup 1.0000x reference)
//
#include <hip/hip_runtime.h>

#define BB 8
#define NN 4096
#define DD 128
#define KK 1024

#define TN  64     // rows per block
#define TKC 256    // k chunk
#define DCH 32     // d chunk

// ---- kernel 1: e2[b][k] = sum_d emb[b][d][k]^2 ----
__global__ void e2_kernel(const float* __restrict__ emb, float* __restrict__ e2) {
  const int b = blockIdx.y;
  const int k = blockIdx.x * 64 + threadIdx.x;
  const float* p = emb + (size_t)b * DD * KK + k;
  float acc = 0.f;
#pragma unroll 8
  for (int d = 0; d < DD; ++d) { float v = p[(size_t)d * KK]; acc += v * v; }
  e2[b * KK + k] = acc;
}

// ---- kernel 2: fused distance GEMM + argmin + gather + loss ----
__launch_bounds__(256, 2)
__global__ void vq_main(const float* __restrict__ x, const float* __restrict__ emb,
                        const float* __restrict__ e2g, float* __restrict__ out) {
  __shared__ float As[DD * TN];      // A[d][r], 32 KB (inner reads are broadcast -> no conflict)
  __shared__ float Bs[DCH * TKC];    // B[dd][k], 32 KB
  int* sidx = (int*)Bs;              // aliased AFTER last Bs use (barrier-protected)

  const int t  = threadIdx.x;
  const int b  = blockIdx.y;
  const int n0 = blockIdx.x * TN;

  const float* xb = x + (size_t)(b * NN + n0) * DD;
  const float* eb = emb + (size_t)b * DD * KK;

  // stage A transposed: As[d*TN + r] = x[b][n0+r][d]  (coalesced global reads)
#pragma unroll
  for (int it = 0; it < (TN * DD) / 256; ++it) {   // 32
    int i = it * 256 + t;
    int r = i >> 7, d = i & 127;
    As[d * TN + r] = xb[i];
  }

  const int tr = t >> 5;   // 0..7  -> rows tr*8 .. tr*8+7
  const int tc = t & 31;   // 0..31 -> cols tc*8 .. tc*8+7 (within k-chunk)

  float minv[8];
  int   mini[8];
#pragma unroll
  for (int j = 0; j < 8; ++j) { minv[j] = 3.4e38f; mini[j] = 0; }

  for (int kc = 0; kc < KK / TKC; ++kc) {          // 4 chunks of 256 k
    float acc[8][8];
#pragma unroll
    for (int j = 0; j < 8; ++j)
#pragma unroll
      for (int m = 0; m < 8; ++m) acc[j][m] = 0.f;

    for (int dc = 0; dc < DD / DCH; ++dc) {        // 4 chunks of 32 d
      __syncthreads();
      {  // stage B chunk: 32 d x 256 k, float4, coalesced
        const float4* g4 = (const float4*)(eb + (size_t)(dc * DCH) * KK + kc * TKC);
        float4* b4 = (float4*)Bs;
#pragma unroll
        for (int it = 0; it < (DCH * TKC / 4) / 256; ++it) {  // 8
          int i  = it * 256 + t;
          int dd = i >> 6, k4 = i & 63;
          b4[dd * (TKC / 4) + k4] = g4[dd * (KK / 4) + k4];
        }
      }
      __syncthreads();
#pragma unroll 8
      for (int dd = 0; dd < DCH; ++dd) {
        const float* arow = &As[(dc * DCH + dd) * TN + tr * 8];
        float4 a0 = *(const float4*)(arow);
        float4 a1 = *(const float4*)(arow + 4);
        const float* brow = &Bs[dd * TKC + tc * 8];
        float4 b0 = *(const float4*)(brow);
        float4 b1 = *(const float4*)(brow + 4);
        float av[8] = {a0.x, a0.y, a0.z, a0.w, a1.x, a1.y, a1.z, a1.w};
        float bv[8] = {b0.x, b0.y, b0.z, b0.w, b1.x, b1.y, b1.z, b1.w};
#pragma unroll
        for (int j = 0; j < 8; ++j)
#pragma unroll
          for (int m = 0; m < 8; ++m)
            acc[j][m] = fmaf(av[j], bv[m], acc[j][m]);
      }
    }
    // epilogue: score = |e|^2 - 2*x.e ; track running argmin (first-index tie-break)
    const int kbase = kc * TKC + tc * 8;
    float4 e0 = *(const float4*)(e2g + b * KK + kbase);
    float4 e1 = *(const float4*)(e2g + b * KK + kbase + 4);
    float ev[8] = {e0.x, e0.y, e0.z, e0.w, e1.x, e1.y, e1.z, e1.w};
#pragma unroll
    for (int j = 0; j < 8; ++j)
#pragma unroll
      for (int m = 0; m < 8; ++m) {
        float s = fmaf(-2.f, acc[j][m], ev[m]);
        if (s < minv[j]) { minv[j] = s; mini[j] = kbase + m; }
      }
  }

  // cross-lane argmin reduce over the 32 tc-lanes (same tr within each half-wave)
#pragma unroll
  for (int off = 1; off < 32; off <<= 1) {
#pragma unroll
    for (int j = 0; j < 8; ++j) {
      float v2 = __shfl_xor(minv[j], off);
      int   i2 = __shfl_xor(mini[j], off);
      if (v2 < minv[j] || (v2 == minv[j] && i2 < mini[j])) { minv[j] = v2; mini[j] = i2; }
    }
  }

  __syncthreads();           // all Bs reads done before aliasing as sidx
  if (tc == 0) {
#pragma unroll
    for (int j = 0; j < 8; ++j) sidx[tr * 8 + j] = mini[j];
  }
  __syncthreads();

  // gather winning embedding column, coalesced store, fused loss
  float lsum = 0.f;
  float* ob = out + (size_t)(b * NN + n0) * DD;
#pragma unroll 4
  for (int it = 0; it < 32; ++it) {
    int i = it * 256 + t;
    int r = i >> 7, d = i & 127;
    int k = sidx[r];
    float q = eb[(size_t)d * KK + k];   // strided but L2-resident (512 KB/batch)
    ob[i] = q;                          // coalesced
    float df = q - As[d * TN + r];
    lsum += df * df;
  }
#pragma unroll
  for (int off = 1; off < 64; off <<= 1) lsum += __shfl_xor(lsum, off);
  if ((t & 63) == 0)
    atomicAdd(out + (size_t)BB * NN * DD, lsum * (1.25f / (float)(BB * NN * DD)));
}

extern "C" void kernel_launch(void* const* d_in, const int* in_sizes, int n_in,
                              void* d_out, int out_size, void* d_ws, size_t ws_size,
                              hipStream_t stream) {
  const float* x   = (const float*)d_in[0];
  const float* emb = (const float*)d_in[1];
  float* out = (float*)d_out;
  float* e2  = (float*)d_ws;   // 8*1024 floats = 32 KB scratch

  // zero the loss accumulator (d_out is poisoned 0xAA before every timed call)
  hipMemsetAsync(out + (size_t)BB * NN * DD, 0, sizeof(float), stream);

  e2_kernel<<<dim3(KK / 64, BB), dim3(64), 0, stream>>>(emb, e2);
  vq_main<<<dim3(NN / TN, BB), dim3(256), 0, stream>>>(x, emb, e2, out);
}

// Round 5
// 124.898 us; speedup vs baseline: 1.7547x; 1.7547x over previous
//
#include <hip/hip_runtime.h>

#define BB 8
#define NN 4096
#define DD 128
#define KK 1024

typedef _Float16 f16;
typedef f16 f16x8 __attribute__((ext_vector_type(8)));
typedef f16 f16x4 __attribute__((ext_vector_type(4)));
typedef float f32x16 __attribute__((ext_vector_type(16)));

#define MFMA32x16 __builtin_amdgcn_mfma_f32_32x32x16_f16

// ---- ws layout ----
// [0,32KB)          e2   f32 [8][1024]
// [32KB, +2MB)      eThi f16 [8][1024][128]
// [+2MB, +4MB)      eTlo f16 [8][1024][128]
// [+4MB, +8MB)      eTf  f32 [8][1024][128]   (exact transpose, for gather)
#define OFF_HI (32768)
#define OFF_LO (32768 + 2097152)
#define OFF_TF (32768 + 4194304)

__device__ __forceinline__ void gload16(const void* g, void* l) {
  __builtin_amdgcn_global_load_lds(
      (const __attribute__((address_space(1))) void*)g,
      (__attribute__((address_space(3))) void*)l, 16, 0, 0);
}

// ================= prep: transpose + f16 hi/lo split + |e|^2 =================
__launch_bounds__(256)
__global__ void vq_prep(const float* __restrict__ emb, char* __restrict__ ws) {
  __shared__ float tile[32][129];     // [k][d], padded: conflict-free col reads
  const int t  = threadIdx.x;
  const int k0 = blockIdx.x * 32;
  const int b  = blockIdx.y;
  float* e2  = (float*)ws;
  f16*   ehi = (f16*)(ws + OFF_HI);
  f16*   elo = (f16*)(ws + OFF_LO);
  float* etf = (float*)(ws + OFF_TF);

  const float* eb = emb + (size_t)b * DD * KK;
#pragma unroll
  for (int it = 0; it < 16; ++it) {   // 128 d x 32 k
    int idx = it * 256 + t;
    int d = idx >> 5, k = idx & 31;
    tile[k][d] = eb[(size_t)d * KK + k0 + k];
  }
  __syncthreads();
#pragma unroll
  for (int rep = 0; rep < 4; ++rep) { // 32 k x 32 float4-segs
    int idx = rep * 256 + t;
    int k = idx >> 5, seg = idx & 31;
    float4 v = *(const float4*)&tile[k][seg * 4];
    size_t base = (size_t)(b * KK + k0 + k) * DD + seg * 4;
    *(float4*)(etf + base) = v;       // exact f32 copy (gather source)
    f16 h0 = (f16)v.x, h1 = (f16)v.y, h2 = (f16)v.z, h3 = (f16)v.w;
    f16x4 hv = {h0, h1, h2, h3};
    f16x4 lv = {(f16)(v.x - (float)h0), (f16)(v.y - (float)h1),
                (f16)(v.z - (float)h2), (f16)(v.w - (float)h3)};
    *(f16x4*)(ehi + base) = hv;
    *(f16x4*)(elo + base) = lv;
  }
  if (t < 32) {                       // |e_k|^2 in f64 (better than np pairwise f32)
    double acc = 0.0;
#pragma unroll 16
    for (int d = 0; d < DD; ++d) { float v = tile[t][d]; acc += (double)v * (double)v; }
    e2[b * KK + k0 + t] = (float)acc;
  }
}

// ============== main: f16x3 MFMA distances + argmin + gather + loss ==========
__launch_bounds__(256, 1)
__global__ void vq_main(const float* __restrict__ x, const char* __restrict__ ws,
                        float* __restrict__ out) {
  // smem: two 32KB B-buffers: [buf][hi 16KB | lo 16KB]; K_STEP=64 rows x 256B
  __shared__ __align__(16) char smem[65536];
  const float* e2g = (const float*)ws;
  const f16*   ehi = (const f16*)(ws + OFF_HI);
  const f16*   elo = (const f16*)(ws + OFF_LO);
  const float* etf = (const float*)(ws + OFF_TF);

  const int t = threadIdx.x;
  const int w = t >> 6, lane = t & 63;
  const int r = lane & 31, hb = lane >> 5;
  const int b = blockIdx.y, n0 = blockIdx.x * 128;

  // ---- A: 32 rows/wave, direct global load + f16 hi/lo split into regs ----
  f16x8 ahi[8], alo[8];
  {
    const float* xrow = x + (size_t)(b * NN + n0 + w * 32 + r) * DD;
#pragma unroll
    for (int dc = 0; dc < 8; ++dc) {
      int d0 = dc * 16 + hb * 8;        // A k-slot: (lane>>5)*8 + j
      float4 f0 = *(const float4*)(xrow + d0);
      float4 f1 = *(const float4*)(xrow + d0 + 4);
      float fv[8] = {f0.x, f0.y, f0.z, f0.w, f1.x, f1.y, f1.z, f1.w};
#pragma unroll
      for (int j = 0; j < 8; ++j) {
        f16 h = (f16)fv[j];
        ahi[dc][j] = h;
        alo[dc][j] = (f16)(fv[j] - (float)h);
      }
    }
  }

  // ---- stage K_STEP=64 rows of eThi/eTlo, pre-swizzled source (m173) ----
  auto STAGE = [&](int buf, int kt) {
    const int k0 = kt * 64;
    char* hbase = smem + buf * 32768;
    char* lbase = hbase + 16384;
#pragma unroll
    for (int i = 0; i < 4; ++i) {
      int c    = i * 4 + w;             // 1KB chunk 0..15
      int rloc = c * 4 + (lane >> 4);   // LDS row this lane's 16B lands in
      int offb = (lane & 15) << 4;      // LDS byte-col within row
      int src  = offb ^ ((rloc & 15) << 4);  // inverse-swizzled global col
      size_t rowb = (size_t)(b * KK + k0 + rloc) << 8;  // 256B rows
      gload16((const char*)ehi + rowb + src, hbase + c * 1024);
      gload16((const char*)elo + rowb + src, lbase + c * 1024);
    }
  };

  float minv[16]; int mink[16];
#pragma unroll
  for (int j = 0; j < 16; ++j) { minv[j] = 3.4e38f; mink[j] = 0; }

  STAGE(0, 0);
  __syncthreads();

  for (int ks = 0; ks < 16; ++ks) {
    const int cur = ks & 1;
    if (ks < 15) STAGE(cur ^ 1, ks + 1);   // prefetch overlaps compute
    const char* hbase = smem + cur * 32768;
    const char* lbase = hbase + 16384;
#pragma unroll
    for (int kc = 0; kc < 2; ++kc) {
      f32x16 accA = {}, accB = {};
      const int krl = kc * 32 + r;          // B col = lane&31
      const int swz = (krl & 15) << 4;
#pragma unroll
      for (int dc = 0; dc < 8; ++dc) {
        const int off = (dc * 32 + hb * 16) ^ swz;   // B k-slot: (lane>>5)*8+j
        f16x8 bh = *(const f16x8*)(hbase + krl * 256 + off);
        f16x8 bl = *(const f16x8*)(lbase + krl * 256 + off);
        accA = MFMA32x16(ahi[dc], bh, accA, 0, 0, 0);
        accA = MFMA32x16(alo[dc], bh, accA, 0, 0, 0);  // reuse bh
        accB = MFMA32x16(ahi[dc], bl, accB, 0, 0, 0);
      }
      const int   kg  = ks * 64 + kc * 32 + r;
      const float e2v = e2g[b * KK + kg];
#pragma unroll
      for (int j = 0; j < 16; ++j) {
        float s = __builtin_fmaf(-2.f, accA[j] + accB[j], e2v);
        if (s < minv[j]) { minv[j] = s; mink[j] = kg; }  // strict <: first index
      }
    }
    __syncthreads();
  }

  // ---- cross-lane argmin over the 32 col-lanes (stays within lane>>5 half) ----
#pragma unroll
  for (int off = 1; off < 32; off <<= 1) {
#pragma unroll
    for (int j = 0; j < 16; ++j) {
      float v2 = __shfl_xor(minv[j], off);
      int   k2 = __shfl_xor(mink[j], off);
      if (v2 < minv[j] || (v2 == minv[j] && k2 < mink[j])) { minv[j] = v2; mink[j] = k2; }
    }
  }
  int* sidx = (int*)smem;                  // alias dead B-buffers
  if (r == 0) {
#pragma unroll
    for (int j = 0; j < 16; ++j) {
      int row = (j & 3) + 8 * (j >> 2) + 4 * hb;   // verified C/D row map (m74/m101)
      sidx[w * 32 + row] = mink[j];
    }
  }
  __syncthreads();

  // ---- gather exact f32 embedding rows, store, fused loss ----
  float lsum = 0.f;
  const float* xb = x + (size_t)(b * NN + n0) * DD;
  float* ob = out + (size_t)(b * NN + n0) * DD;
#pragma unroll
  for (int rep = 0; rep < 16; ++rep) {
    int idx = rep * 256 + t;
    int row = idx >> 5, seg = idx & 31;
    int k = sidx[row];
    float4 q  = *(const float4*)(etf + (size_t)(b * KK + k) * DD + seg * 4);
    float4 xv = *(const float4*)(xb + row * DD + seg * 4);
    *(float4*)(ob + row * DD + seg * 4) = q;
    float d0 = q.x - xv.x, d1 = q.y - xv.y, d2 = q.z - xv.z, d3 = q.w - xv.w;
    lsum += d0 * d0 + d1 * d1 + d2 * d2 + d3 * d3;
  }
#pragma unroll
  for (int off = 1; off < 64; off <<= 1) lsum += __shfl_xor(lsum, off);
  if (lane == 0)
    atomicAdd(out + (size_t)BB * NN * DD,
              lsum * (1.25f / (float)((size_t)BB * NN * DD)));
}

extern "C" void kernel_launch(void* const* d_in, const int* in_sizes, int n_in,
                              void* d_out, int out_size, void* d_ws, size_t ws_size,
                              hipStream_t stream) {
  const float* x   = (const float*)d_in[0];
  const float* emb = (const float*)d_in[1];
  float* out = (float*)d_out;
  char*  ws  = (char*)d_ws;

  hipMemsetAsync(out + (size_t)BB * NN * DD, 0, sizeof(float), stream);
  vq_prep<<<dim3(KK / 32, BB), 256, 0, stream>>>(emb, ws);
  vq_main<<<dim3(NN / 128, BB), 256, 0, stream>>>(x, ws, out);
}